// Round 7
// baseline (253.931 us; speedup 1.0000x reference)
//
#include <hip/hip_runtime.h>
#include <math.h>

#define NB 8
#define CIN 256
#define CR 64
#define H 64
#define W 64
#define HW 4096

typedef _Float16 f16;
typedef _Float16 f16x8 __attribute__((ext_vector_type(8)));
typedef _Float16 f16x4 __attribute__((ext_vector_type(4)));
typedef float f32x4 __attribute__((ext_vector_type(4)));
typedef float f32x16 __attribute__((ext_vector_type(16)));
typedef unsigned int u32;
typedef unsigned int u32x4 __attribute__((ext_vector_type(4)));

static const size_t QKV = (size_t)NB * CR * HW;   // 2,097,152 elems per q/k/v buffer

// async global->LDS, 16B per lane, LDS dest = uniform base + lane*16
static __device__ __forceinline__ void gl_lds16(const f16* g, f16* l) {
    __builtin_amdgcn_global_load_lds(
        (const __attribute__((address_space(1))) void*)g,
        (__attribute__((address_space(3))) void*)l, 16, 0, 0);
}

static __device__ __forceinline__ u32 pk2(float a, float b) {
    return __builtin_bit_cast(u32, __builtin_amdgcn_cvt_pkrtz(a, b));
}

static __device__ __forceinline__ f32x16 zero16() {
    f32x16 v;
#pragma unroll
    for (int i = 0; i < 16; ++i) v[i] = 0.f;
    return v;
}

// ------------------------------------------------------------- weight prep
// w[co][ci][dy][dx] fp32 -> wT[dy*K+dx][co][ci] fp16
__global__ __launch_bounds__(256) void prep_w(
    const float* __restrict__ src, f16* __restrict__ dst, int KK)
{
    int idx = blockIdx.x * 256 + threadIdx.x;    // < 64*256*KK
    int ci = idx & 255;
    int co = (idx >> 8) & 63;
    int off = idx >> 14;
    dst[((size_t)(off * 64 + co)) * 256 + ci] = (f16)src[((size_t)(co * 256 + ci)) * KK + off];
}

// ------------------------------------------------------- feature-map transpose
// fm f32 [n][ci][y][x] -> fmT f16 [n][y*64+x][ci]
__global__ __launch_bounds__(256) void transpose_fm(
    const float* __restrict__ fm, f16* __restrict__ fmT)
{
    const int y = blockIdx.x & 63;
    const int n = blockIdx.x >> 6;
    const int tid = threadIdx.x;
    __shared__ f16x4 tile[64 * 64];   // [x][slot], slot XOR-swizzled by x
    const int xw = tid & 63;
    const int wv = tid >> 6;
    const float* s0 = fm + ((size_t)n * CIN) * HW + y * W + xw;
#pragma unroll
    for (int cc = 0; cc < 16; ++cc) {
        const int slot = wv * 16 + cc;            // ci = slot*4 + e
        const float* s = s0 + (size_t)(slot * 4) * HW;
        f16x4 pk;
#pragma unroll
        for (int e = 0; e < 4; ++e) pk[e] = (f16)s[(size_t)e * HW];
        tile[xw * 64 + (slot ^ xw)] = pk;
    }
    __syncthreads();
    f16x4* dst = (f16x4*)fmT + ((size_t)n * HW + y * W) * 64;
#pragma unroll
    for (int it = 0; it < 16; ++it) {
        const int idx = tid + it * 256;           // < 4096
        const int x = idx >> 6;
        const int slot = idx & 63;
        dst[x * 64 + slot] = tile[x * 64 + (slot ^ x)];
    }
}

// ---------------------------------------------------------- MFMA conv K x K
// Grid 256 blocks (n, 2-row group), 512 threads = 8 waves (row r, co-half h, k-half sw).
// LAYOUT 0: dst [n][p][c] f16 (q, k).  LAYOUT 1: dst [n][c][p] f16 (v).
// oscale: output scale (log2e for q to move softmax into exp2 domain).
template<int K, int LAYOUT>
__global__ __launch_bounds__(512) void conv_mfma(
    const f16* __restrict__ fmT, const f16* __restrict__ wT,
    const float* __restrict__ bias, f16* __restrict__ dst, float oscale)
{
    constexpr int P = K / 2;
    constexpr int XBYTES = 2 * 72 * 128;          // 18432
    constexpr int WBYTES = K * 64 * 128;
    constexpr int TBYTES = XBYTES + WBYTES;
    constexpr int SBYTES = (TBYTES > 32768) ? TBYTES : 32768;
    __shared__ __align__(16) unsigned char smem[SBYTES];
    unsigned char* Xl = smem;
    unsigned char* Wl = smem + XBYTES;

    const int bid0 = blockIdx.x;
    const int bid = (bid0 & 7) * 32 + (bid0 >> 3);   // XCD swizzle, 256 = 8*32
    const int n  = bid >> 5;
    const int y0 = (bid & 31) * 2;
    const int tid = threadIdx.x;
    const int w = tid >> 6;
    const int lane = tid & 63;
    const int r  = w >> 2;        // row within block
    const int h  = (w >> 1) & 1;  // co half
    const int sw = w & 1;         // k half (32-ci sub-chunk)
    const int lm = lane & 15;
    const int g  = lane >> 4;

    // zero halo columns once (cols [0,P) and [64+P,72) of both slots)
    if (tid < 128) {
        const int sl = tid >> 6;
        const int cidx = (tid >> 3) & 7;
        const int chunk = tid & 7;
        const int col = (cidx < P) ? cidx : (64 + cidx);
        *(uint4*)(Xl + (size_t)(sl * 72 + col) * 128 + chunk * 16) = uint4{0, 0, 0, 0};
    }

    f32x4 acc[2][4];
#pragma unroll
    for (int i = 0; i < 2; ++i)
#pragma unroll
        for (int j = 0; j < 4; ++j) acc[i][j] = f32x4{0.f, 0.f, 0.f, 0.f};

    for (int dy = 0; dy < K; ++dy) {
        for (int ch = 0; ch < 4; ++ch) {
            __syncthreads();
            // ---- stage X: 2 rows x 64 x x 64 ci(ch) = 1024 uint4, 2/thread
#pragma unroll
            for (int p = 0; p < 2; ++p) {
                const int idx = tid + p * 512;
                const int sl = idx >> 9;
                const int x = (idx >> 3) & 63;
                const int chunk = idx & 7;
                const int iy = y0 + sl + dy - P;
                uint4 val = uint4{0, 0, 0, 0};
                if (iy >= 0 && iy < H)
                    val = *(const uint4*)(fmT + ((size_t)n * HW + iy * 64 + x) * 256 +
                                          ch * 64 + chunk * 8);
                *(uint4*)(Xl + (size_t)(sl * 72 + x + P) * 128 +
                          ((chunk * 16) ^ (((x + P) & 7) << 4))) = val;
            }
            // ---- stage W: K*512 uint4, K/thread
#pragma unroll
            for (int p = 0; p < K; ++p) {
                const int idx = tid + p * 512;
                const int cig = idx & 7;
                const int co  = (idx >> 3) & 63;
                const int dx  = idx >> 9;
                const f16* s = wT + ((size_t)((dy * K + dx) * 64 + co)) * 256 + ch * 64 + cig * 8;
                *(uint4*)(Wl + (size_t)(dx * 64 + co) * 128 +
                          ((cig * 16) ^ ((co & 7) << 4))) = *(const uint4*)s;
            }
            __syncthreads();
            // ---- compute
#pragma unroll
            for (int dx = 0; dx < K; ++dx) {
                f16x8 a[2], b[4];
#pragma unroll
                for (int cf = 0; cf < 2; ++cf) {
                    const int co = h * 32 + cf * 16 + lm;
                    a[cf] = *(const f16x8*)(Wl + (size_t)(dx * 64 + co) * 128 +
                                            ((sw * 64 + g * 16) ^ ((co & 7) << 4)));
                }
#pragma unroll
                for (int xf = 0; xf < 4; ++xf) {
                    const int col = xf * 16 + lm + dx;
                    b[xf] = *(const f16x8*)(Xl + (size_t)(r * 72 + col) * 128 +
                                            ((sw * 64 + g * 16) ^ ((col & 7) << 4)));
                }
#pragma unroll
                for (int cf = 0; cf < 2; ++cf)
#pragma unroll
                    for (int xf = 0; xf < 4; ++xf)
                        acc[cf][xf] = __builtin_amdgcn_mfma_f32_16x16x32_f16(
                            a[cf], b[xf], acc[cf][xf], 0, 0, 0);
            }
        }
    }

    // ---- merge k-halves
    __syncthreads();
    {
        const int mslot = r * 2 + h;
        if (sw == 1) {
#pragma unroll
            for (int cf = 0; cf < 2; ++cf)
#pragma unroll
                for (int xf = 0; xf < 4; ++xf)
                    *(f32x4*)(smem + (size_t)(mslot * 64 + lane) * 128 +
                              (((cf * 4 + xf) * 16) ^ ((lane & 7) << 4))) = acc[cf][xf];
        }
        __syncthreads();
        if (sw == 0) {
#pragma unroll
            for (int cf = 0; cf < 2; ++cf)
#pragma unroll
                for (int xf = 0; xf < 4; ++xf)
                    acc[cf][xf] += *(const f32x4*)(smem + (size_t)(mslot * 64 + lane) * 128 +
                                                   (((cf * 4 + xf) * 16) ^ ((lane & 7) << 4)));
        }
    }

    // ---- epilogue (sw=0 waves)
    if (sw == 0) {
        const int y = y0 + r;
#pragma unroll
        for (int cf = 0; cf < 2; ++cf) {
            const float4 bv = *(const float4*)(bias + h * 32 + cf * 16 + g * 4);
            if (LAYOUT == 0) {
#pragma unroll
                for (int xf = 0; xf < 4; ++xf) {
                    f16x4 pk;
#pragma unroll
                    for (int e = 0; e < 4; ++e)
                        pk[e] = (f16)((acc[cf][xf][e] + ((const float*)&bv)[e]) * oscale);
                    *(f16x4*)(dst + ((size_t)n * HW + y * W + xf * 16 + lm) * 64 +
                              h * 32 + cf * 16 + g * 4) = pk;
                }
            } else {
#pragma unroll
                for (int e = 0; e < 4; ++e) {
                    const int co = h * 32 + cf * 16 + g * 4 + e;
#pragma unroll
                    for (int xf = 0; xf < 4; ++xf)
                        dst[((size_t)(n * CR + co)) * HW + y * W + xf * 16 + lm] =
                            (f16)((acc[cf][xf][e] + ((const float*)&bv)[e]) * oscale);
                }
            }
        }
    }
}

// ------------------------------------------------- fused MFMA attention (32x32)
// Grid 256 (n, 128-j tile), 4 waves; wave owns 32 j = jb*128 + wv*32 + (lane&31).
// Q in registers; K/V double-buffered in LDS via global_load_lds (pre-swizzled src);
// softmax in exp2 domain (q pre-scaled by log2e), per-column m,z in registers.
__global__ __launch_bounds__(256, 1) void attn_mfma(
    const f16* __restrict__ qT, const f16* __restrict__ kT, const f16* __restrict__ vv,
    f16* __restrict__ attu, float* __restrict__ Mcol, float* __restrict__ Zcol)
{
    const int bid0 = blockIdx.x;
    const int bid = (bid0 & 7) * 32 + (bid0 >> 3);   // XCD swizzle: n == XCD
    const int n  = bid >> 5;
    const int jb = bid & 31;
    const int tid = threadIdx.x;
    const int wv = tid >> 6;
    const int lane = tid & 63;
    const int lm5 = lane & 31;
    const int g1 = lane >> 5;
    const int j = jb * 128 + wv * 32 + lm5;
    const int key = (lm5 & 7) << 4;

    __shared__ __align__(16) f16 KV[2][2][64 * 64];   // [buf][K/V][row 128B x64]

    // per-lane staging source perm (pre-swizzle so linear LDS dest ends up XOR'd)
    const int rsub = lane >> 3;                 // row within 8-row chunk
    const int perm = ((lane & 7) ^ rsub) << 3;  // f16 units
    const f16* kS = kT + ((size_t)n * HW) * 64;
    const f16* vS = vv + ((size_t)n * CR) * HW;

    // Q fragments: B col=j (lane&31), k = ks*16 + g1*8 + e
    f16x8 qf[4];
    {
        const f16* qp = qT + ((size_t)n * HW + j) * 64 + g1 * 8;
#pragma unroll
        for (int ks = 0; ks < 4; ++ks) qf[ks] = *(const f16x8*)(qp + ks * 16);
    }

    float m = -1e30f, z = 0.f;
    f32x16 acc0 = zero16(), acc1 = zero16();

    // prologue: stage tile 0 into buf 0 (4 chunks of 1KB per wave)
#pragma unroll
    for (int h = 0; h < 2; ++h) {
        const int q = 2 * wv + h;
        gl_lds16(kS + (size_t)(q * 8 + rsub) * 64 + perm, &KV[0][0][q * 512]);
        gl_lds16(vS + (size_t)(q * 8 + rsub) * HW + perm, &KV[0][1][q * 512]);
    }
    __syncthreads();

    int buf = 0;
    for (int it = 0; it < 64; ++it) {
        // ---- QK: S[i][j] (two 32-i tiles), A=K from LDS, B=Q regs
        const char* Kb = (const char*)&KV[buf][0][0];
        f32x16 s0 = zero16(), s1 = zero16();
        __builtin_amdgcn_s_setprio(1);
#pragma unroll
        for (int ks = 0; ks < 4; ++ks) {
            const int off = ((ks * 32 + g1 * 16) ^ key);
            const f16x8 A0 = *(const f16x8*)(Kb + lm5 * 128 + off);
            const f16x8 A1 = *(const f16x8*)(Kb + (32 + lm5) * 128 + off);
            s0 = __builtin_amdgcn_mfma_f32_32x32x16_f16(A0, qf[ks], s0, 0, 0, 0);
            s1 = __builtin_amdgcn_mfma_f32_32x32x16_f16(A1, qf[ks], s1, 0, 0, 0);
        }
        __builtin_amdgcn_s_setprio(0);

        // ---- prefetch next tile into buf^1 (in flight across softmax+PV)
        if (it < 63) {
#pragma unroll
            for (int h = 0; h < 2; ++h) {
                const int q = 2 * wv + h;
                gl_lds16(kS + (size_t)((it + 1) * 64 + q * 8 + rsub) * 64 + perm,
                         &KV[buf ^ 1][0][q * 512]);
                gl_lds16(vS + (size_t)(q * 8 + rsub) * HW + (it + 1) * 64 + perm,
                         &KV[buf ^ 1][1][q * 512]);
            }
        }

        // ---- online softmax (exp2 domain); column j is lane-local (pair g1=0/1)
        float mt = s0[0];
#pragma unroll
        for (int rr2 = 1; rr2 < 16; ++rr2) mt = fmaxf(mt, s0[rr2]);
#pragma unroll
        for (int rr2 = 0; rr2 < 16; ++rr2) mt = fmaxf(mt, s1[rr2]);
        mt = fmaxf(mt, __shfl_xor(mt, 32));
        if (__ballot(mt > m)) {            // defer-max: skip rescale when no growth
            const float mnew = fmaxf(m, mt);
            const float rsc = exp2f(m - mnew);
            z *= rsc;
#pragma unroll
            for (int rr2 = 0; rr2 < 16; ++rr2) { acc0[rr2] *= rsc; acc1[rr2] *= rsc; }
            m = mnew;
        }
        float zt = 0.f;
        u32 pa0[8], pa1[8];                // packed P (f16 pairs), per i-tile
#pragma unroll
        for (int a = 0; a < 4; ++a) {
            float p0 = exp2f(s0[4 * a + 0] - m), p1 = exp2f(s0[4 * a + 1] - m);
            float p2 = exp2f(s0[4 * a + 2] - m), p3 = exp2f(s0[4 * a + 3] - m);
            zt += (p0 + p1) + (p2 + p3);
            pa0[a * 2 + 0] = pk2(p0, p1); pa0[a * 2 + 1] = pk2(p2, p3);
            float q0 = exp2f(s1[4 * a + 0] - m), q1 = exp2f(s1[4 * a + 1] - m);
            float q2 = exp2f(s1[4 * a + 2] - m), q3 = exp2f(s1[4 * a + 3] - m);
            zt += (q0 + q1) + (q2 + q3);
            pa1[a * 2 + 0] = pk2(q0, q1); pa1[a * 2 + 1] = pk2(q2, q3);
        }
        zt += __shfl_xor(zt, 32);
        z += zt;

        // ---- repack P into x32 B-frags: k = i = ks2*16 + g1*8 + e
        // own D rows: i = itile*32 + 8a + 4*g1 + (0..3); partner (lane^32) has +-4 blocks
        u32 bfu[4][4];
#pragma unroll
        for (int it2 = 0; it2 < 2; ++it2) {
            const u32* P = (it2 == 0) ? pa0 : pa1;
#pragma unroll
            for (int k2 = 0; k2 < 2; ++k2) {
                const u32 sA = g1 ? P[(k2 * 2 + 0) * 2 + 0] : P[(k2 * 2 + 1) * 2 + 0];
                const u32 sB = g1 ? P[(k2 * 2 + 0) * 2 + 1] : P[(k2 * 2 + 1) * 2 + 1];
                const u32 rA = __shfl_xor(sA, 32);
                const u32 rB = __shfl_xor(sB, 32);
                const u32 oA = g1 ? P[(k2 * 2 + 1) * 2 + 0] : P[(k2 * 2 + 0) * 2 + 0];
                const u32 oB = g1 ? P[(k2 * 2 + 1) * 2 + 1] : P[(k2 * 2 + 0) * 2 + 1];
                bfu[it2 * 2 + k2][0] = g1 ? rA : oA;
                bfu[it2 * 2 + k2][1] = g1 ? rB : oB;
                bfu[it2 * 2 + k2][2] = g1 ? oA : rA;
                bfu[it2 * 2 + k2][3] = g1 ? oB : rB;
            }
        }

        // ---- PV: att[c][j] += V[c][i] * P[i][j]
        const char* Vb = (const char*)&KV[buf][1][0];
        __builtin_amdgcn_s_setprio(1);
#pragma unroll
        for (int ks2 = 0; ks2 < 4; ++ks2) {
            const f16x8 B = __builtin_bit_cast(
                f16x8, (u32x4){bfu[ks2][0], bfu[ks2][1], bfu[ks2][2], bfu[ks2][3]});
            const int off = ((ks2 * 32 + g1 * 16) ^ key);
            const f16x8 A0 = *(const f16x8*)(Vb + lm5 * 128 + off);
            const f16x8 A1 = *(const f16x8*)(Vb + (32 + lm5) * 128 + off);
            acc0 = __builtin_amdgcn_mfma_f32_32x32x16_f16(A0, B, acc0, 0, 0, 0);
            acc1 = __builtin_amdgcn_mfma_f32_32x32x16_f16(A1, B, acc1, 0, 0, 0);
        }
        __builtin_amdgcn_s_setprio(0);

        if (it < 63) {
            __syncthreads();   // drains prefetch vmcnt + all waves done with buf
            buf ^= 1;
        }
    }

    // epilogue: attu[n][j][c] f16; c = ct*32 + 8a + 4*g1 + e
    const size_t jbase = ((size_t)n * HW + j) * 64;
#pragma unroll
    for (int a = 0; a < 4; ++a) {
        f16x4 pk0, pk1;
#pragma unroll
        for (int e = 0; e < 4; ++e) { pk0[e] = (f16)acc0[4 * a + e]; pk1[e] = (f16)acc1[4 * a + e]; }
        *(f16x4*)(attu + jbase + a * 8 + g1 * 4) = pk0;
        *(f16x4*)(attu + jbase + 32 + a * 8 + g1 * 4) = pk1;
    }
    if (g1 == 0) {
        Mcol[(size_t)n * HW + j] = m;   // log2 domain
        Zcol[(size_t)n * HW + j] = z;
    }
}

// ------------------------------------------------------------- global M, Z per n
__global__ __launch_bounds__(256) void reduce_kernel(
    const float* __restrict__ Mcol, const float* __restrict__ Zcol,
    float* __restrict__ Mn, float* __restrict__ Zn)
{
    const int n = blockIdx.x;
    const int tid = threadIdx.x;
    __shared__ float red[256];

    float lm = -1e30f;
    for (int j = tid; j < HW; j += 256) lm = fmaxf(lm, Mcol[(size_t)n * HW + j]);
    red[tid] = lm; __syncthreads();
    for (int s = 128; s > 0; s >>= 1) {
        if (tid < s) red[tid] = fmaxf(red[tid], red[tid + s]);
        __syncthreads();
    }
    const float M = red[0];
    __syncthreads();

    float ls = 0.f;
    for (int j = tid; j < HW; j += 256)
        ls += Zcol[(size_t)n * HW + j] * exp2f(Mcol[(size_t)n * HW + j] - M);
    red[tid] = ls; __syncthreads();
    for (int s = 128; s > 0; s >>= 1) {
        if (tid < s) red[tid] += red[tid + s];
        __syncthreads();
    }
    if (tid == 0) { Mn[n] = M; Zn[n] = red[0]; }
}

// --------------------- MFMA 1x1 conv + per-column scale + elementwise
__global__ __launch_bounds__(512) void final_mfma(
    const f16* __restrict__ attu, const float* __restrict__ Mcol,
    const float* __restrict__ Mn, const float* __restrict__ Zn,
    const float* __restrict__ watt, const float* __restrict__ batt,
    const float* __restrict__ gco, float* __restrict__ out)
{
    __shared__ __align__(16) f16 Wl[256 * 64];   // 32 KB
    __shared__ __align__(16) f16 Al[128 * 64];   // 16 KB

    const int bid0 = blockIdx.x;
    const int bid = (bid0 & 7) * 32 + (bid0 >> 3);   // XCD swizzle: n == XCD
    const int n  = bid >> 5;
    const int p0 = (bid & 31) * 128;
    const int tid = threadIdx.x;
    const int wv = tid >> 6;
    const int lane = tid & 63;
    const int lm = lane & 15;
    const int g  = lane >> 4;

#pragma unroll
    for (int t = 0; t < 8; ++t) {
        const int idx = tid + t * 512;
        const int co = idx >> 4;
        const int ch = idx & 15;
        const float4 w4 = *(const float4*)(watt + (size_t)co * 64 + ch * 4);
        f16x4 pk;
        pk[0] = (f16)w4.x; pk[1] = (f16)w4.y; pk[2] = (f16)w4.z; pk[3] = (f16)w4.w;
        *(f16x4*)((char*)Wl + co * 128 + ((ch * 8) ^ ((co & 7) << 4))) = pk;
    }
#pragma unroll
    for (int t = 0; t < 4; ++t) {
        const int idx = tid + t * 512;
        const int pp = idx >> 3;
        const int ch = idx & 7;
        *(uint4*)((char*)Al + pp * 128 + ((ch * 16) ^ ((pp & 7) << 4))) =
            *(const uint4*)(attu + ((size_t)n * HW + p0 + pp) * 64 + ch * 8);
    }
    __syncthreads();

    f32x4 acc[2][8];
#pragma unroll
    for (int cf = 0; cf < 2; ++cf)
#pragma unroll
        for (int pf = 0; pf < 8; ++pf) acc[cf][pf] = f32x4{0.f, 0.f, 0.f, 0.f};

#pragma unroll
    for (int ks = 0; ks < 2; ++ks) {
        const int off = ks * 64 + g * 16;
        f16x8 A[2], B[8];
#pragma unroll
        for (int cf = 0; cf < 2; ++cf) {
            const int co = wv * 32 + cf * 16 + lm;
            A[cf] = *(const f16x8*)((char*)Wl + co * 128 + (off ^ ((co & 7) << 4)));
        }
#pragma unroll
        for (int pf = 0; pf < 8; ++pf) {
            const int pp = pf * 16 + lm;
            B[pf] = *(const f16x8*)((char*)Al + pp * 128 + (off ^ ((pp & 7) << 4)));
        }
#pragma unroll
        for (int cf = 0; cf < 2; ++cf)
#pragma unroll
            for (int pf = 0; pf < 8; ++pf)
                acc[cf][pf] = __builtin_amdgcn_mfma_f32_16x16x32_f16(
                    A[cf], B[pf], acc[cf][pf], 0, 0, 0);
    }

    const float M = Mn[n];
    const float Zi = 1.f / Zn[n];
    float ecol[8];
#pragma unroll
    for (int pf = 0; pf < 8; ++pf)
        ecol[pf] = exp2f(Mcol[(size_t)n * HW + p0 + pf * 16 + lm] - M) * Zi;

#pragma unroll
    for (int cf = 0; cf < 2; ++cf) {
#pragma unroll
        for (int e = 0; e < 4; ++e) {
            const int co = wv * 32 + cf * 16 + g * 4 + e;
            const float bb = batt[co] + 1.f;
            const float* gsrc = gco + (size_t)(n * CIN + co) * HW + p0 + lm;
            float* dstp = out + (size_t)(n * CIN + co) * HW + p0 + lm;
#pragma unroll
            for (int pf = 0; pf < 8; ++pf) {
                const float gvv = gsrc[pf * 16];
                dstp[pf * 16] = gvv * (acc[cf][pf][e] * ecol[pf] + bb);
            }
        }
    }
}

// --------------------------------------------------------------------- launch
extern "C" void kernel_launch(void* const* d_in, const int* in_sizes, int n_in,
                              void* d_out, int out_size, void* d_ws, size_t ws_size,
                              hipStream_t stream)
{
    (void)in_sizes; (void)n_in; (void)out_size; (void)ws_size;
    const float* fm   = (const float*)d_in[0];
    const float* gco  = (const float*)d_in[1];
    const float* wq   = (const float*)d_in[2];
    const float* bq   = (const float*)d_in[3];
    const float* wk   = (const float*)d_in[4];
    const float* bk   = (const float*)d_in[5];
    const float* wv   = (const float*)d_in[6];
    const float* bv   = (const float*)d_in[7];
    const float* watt = (const float*)d_in[8];
    const float* batt = (const float*)d_in[9];
    float* out = (float*)d_out;

    // f16 scratch in d_out (28.8 MB of 33.5 MB): qT|kT|v|fmT, all dead before final.
    f16* qT   = (f16*)out;            // [n][p][c]   4 MB  (pre-scaled by log2e)
    f16* kT   = qT + QKV;             // [n][p][c]   4 MB
    f16* vvb  = kT + QKV;             // [n][c][p]   4 MB
    f16* fmT  = vvb + QKV;            // [n][p][ci]  16.8 MB

    // ws: wTq | wTk | wTv | attu | Mcol | Zcol | Mn | Zn  (7.18 MB, proven layout)
    unsigned char* wsb = (unsigned char*)d_ws;
    f16* wTq = (f16*)(wsb);
    f16* wTk = (f16*)(wsb + 294912);
    f16* wTv = (f16*)(wsb + 1114112);
    f16* attu = (f16*)(wsb + 2719744);                        // [n][p][c] f16, 4 MB
    float* Mcol = (float*)(wsb + 6914048);                    // [n][4096] f32 (log2)
    float* Zcol = (float*)(wsb + 7045120);
    float* Mn   = (float*)(wsb + 7176192);
    float* Zn   = (float*)(wsb + 7176224);

    const float LOG2E = 1.4426950408889634f;

    prep_w<<<576, 256, 0, stream>>>(wq, wTq, 9);
    prep_w<<<1600, 256, 0, stream>>>(wk, wTk, 25);
    prep_w<<<3136, 256, 0, stream>>>(wv, wTv, 49);
    transpose_fm<<<NB * 64, 256, 0, stream>>>(fm, fmT);

    conv_mfma<3, 0><<<256, 512, 0, stream>>>(fmT, wTq, bq, qT, LOG2E);
    conv_mfma<5, 0><<<256, 512, 0, stream>>>(fmT, wTk, bk, kT, 1.0f);
    conv_mfma<7, 1><<<256, 512, 0, stream>>>(fmT, wTv, bv, vvb, 1.0f);

    attn_mfma<<<256, 256, 0, stream>>>(qT, kT, vvb, attu, Mcol, Zcol);
    reduce_kernel<<<NB, 256, 0, stream>>>(Mcol, Zcol, Mn, Zn);
    final_mfma<<<256, 512, 0, stream>>>(attu, Mcol, Mn, Zn, watt, batt, gco, out);
}

// Round 8
// 239.597 us; speedup vs baseline: 1.0598x; 1.0598x over previous
//
#include <hip/hip_runtime.h>
#include <math.h>

#define NB 8
#define CIN 256
#define CR 64
#define H 64
#define W 64
#define HW 4096

typedef _Float16 f16;
typedef _Float16 f16x8 __attribute__((ext_vector_type(8)));
typedef _Float16 f16x4 __attribute__((ext_vector_type(4)));
typedef float f32x4 __attribute__((ext_vector_type(4)));

static const size_t QKV = (size_t)NB * CR * HW;   // 2,097,152 elems per q/k/v buffer

// async global->LDS, 16B per lane, LDS dest = uniform base + lane*16
static __device__ __forceinline__ void gl_lds16(const f16* g, f16* l) {
    __builtin_amdgcn_global_load_lds(
        (const __attribute__((address_space(1))) void*)g,
        (__attribute__((address_space(3))) void*)l, 16, 0, 0);
}

// ------------------------------------------------------------- weight prep
// w[co][ci][dy][dx] fp32 -> wT[dy*K+dx][co][ci] fp16
__global__ __launch_bounds__(256) void prep_w(
    const float* __restrict__ src, f16* __restrict__ dst, int KK)
{
    int idx = blockIdx.x * 256 + threadIdx.x;    // < 64*256*KK
    int ci = idx & 255;
    int co = (idx >> 8) & 63;
    int off = idx >> 14;
    dst[((size_t)(off * 64 + co)) * 256 + ci] = (f16)src[((size_t)(co * 256 + ci)) * KK + off];
}

// ------------------------------------------------------- feature-map transpose
// fm f32 [n][ci][y][x] -> fmT f16 [n][y*64+x][ci]
__global__ __launch_bounds__(256) void transpose_fm(
    const float* __restrict__ fm, f16* __restrict__ fmT)
{
    const int y = blockIdx.x & 63;
    const int n = blockIdx.x >> 6;
    const int tid = threadIdx.x;
    __shared__ f16x4 tile[64 * 64];   // [x][slot], slot XOR-swizzled by x
    const int xw = tid & 63;
    const int wv = tid >> 6;
    const float* s0 = fm + ((size_t)n * CIN) * HW + y * W + xw;
#pragma unroll
    for (int cc = 0; cc < 16; ++cc) {
        const int slot = wv * 16 + cc;            // ci = slot*4 + e
        const float* s = s0 + (size_t)(slot * 4) * HW;
        f16x4 pk;
#pragma unroll
        for (int e = 0; e < 4; ++e) pk[e] = (f16)s[(size_t)e * HW];
        tile[xw * 64 + (slot ^ xw)] = pk;
    }
    __syncthreads();
    f16x4* dst = (f16x4*)fmT + ((size_t)n * HW + y * W) * 64;
#pragma unroll
    for (int it = 0; it < 16; ++it) {
        const int idx = tid + it * 256;           // < 4096
        const int x = idx >> 6;
        const int slot = idx & 63;
        dst[x * 64 + slot] = tile[x * 64 + (slot ^ x)];
    }
}

// ---------------------------------------------------------- MFMA conv K x K
// Grid 256 blocks (n, 2-row group), 512 threads = 8 waves (row r, co-half h, k-half sw).
// LAYOUT 0: dst [n][p][c] f16 (q, k).  LAYOUT 1: dst [n][c][p] f16 (v).
// oscale: output scale (log2e for q to move softmax into exp2 domain).
template<int K, int LAYOUT>
__global__ __launch_bounds__(512) void conv_mfma(
    const f16* __restrict__ fmT, const f16* __restrict__ wT,
    const float* __restrict__ bias, f16* __restrict__ dst, float oscale)
{
    constexpr int P = K / 2;
    constexpr int XBYTES = 2 * 72 * 128;          // 18432
    constexpr int WBYTES = K * 64 * 128;
    constexpr int TBYTES = XBYTES + WBYTES;
    constexpr int SBYTES = (TBYTES > 32768) ? TBYTES : 32768;
    __shared__ __align__(16) unsigned char smem[SBYTES];
    unsigned char* Xl = smem;
    unsigned char* Wl = smem + XBYTES;

    const int bid0 = blockIdx.x;
    const int bid = (bid0 & 7) * 32 + (bid0 >> 3);   // XCD swizzle, 256 = 8*32
    const int n  = bid >> 5;
    const int y0 = (bid & 31) * 2;
    const int tid = threadIdx.x;
    const int w = tid >> 6;
    const int lane = tid & 63;
    const int r  = w >> 2;        // row within block
    const int h  = (w >> 1) & 1;  // co half
    const int sw = w & 1;         // k half (32-ci sub-chunk)
    const int lm = lane & 15;
    const int g  = lane >> 4;

    // zero halo columns once (cols [0,P) and [64+P,72) of both slots)
    if (tid < 128) {
        const int sl = tid >> 6;
        const int cidx = (tid >> 3) & 7;
        const int chunk = tid & 7;
        const int col = (cidx < P) ? cidx : (64 + cidx);
        *(uint4*)(Xl + (size_t)(sl * 72 + col) * 128 + chunk * 16) = uint4{0, 0, 0, 0};
    }

    f32x4 acc[2][4];
#pragma unroll
    for (int i = 0; i < 2; ++i)
#pragma unroll
        for (int jx = 0; jx < 4; ++jx) acc[i][jx] = f32x4{0.f, 0.f, 0.f, 0.f};

    for (int dy = 0; dy < K; ++dy) {
        for (int ch = 0; ch < 4; ++ch) {
            __syncthreads();
            // ---- stage X: 2 rows x 64 x x 64 ci(ch) = 1024 uint4, 2/thread
#pragma unroll
            for (int p = 0; p < 2; ++p) {
                const int idx = tid + p * 512;
                const int sl = idx >> 9;
                const int x = (idx >> 3) & 63;
                const int chunk = idx & 7;
                const int iy = y0 + sl + dy - P;
                uint4 val = uint4{0, 0, 0, 0};
                if (iy >= 0 && iy < H)
                    val = *(const uint4*)(fmT + ((size_t)n * HW + iy * 64 + x) * 256 +
                                          ch * 64 + chunk * 8);
                *(uint4*)(Xl + (size_t)(sl * 72 + x + P) * 128 +
                          ((chunk * 16) ^ (((x + P) & 7) << 4))) = val;
            }
            // ---- stage W: K*512 uint4, K/thread
#pragma unroll
            for (int p = 0; p < K; ++p) {
                const int idx = tid + p * 512;
                const int cig = idx & 7;
                const int co  = (idx >> 3) & 63;
                const int dx  = idx >> 9;
                const f16* s = wT + ((size_t)((dy * K + dx) * 64 + co)) * 256 + ch * 64 + cig * 8;
                *(uint4*)(Wl + (size_t)(dx * 64 + co) * 128 +
                          ((cig * 16) ^ ((co & 7) << 4))) = *(const uint4*)s;
            }
            __syncthreads();
            // ---- compute
#pragma unroll
            for (int dx = 0; dx < K; ++dx) {
                f16x8 a[2], b[4];
#pragma unroll
                for (int cf = 0; cf < 2; ++cf) {
                    const int co = h * 32 + cf * 16 + lm;
                    a[cf] = *(const f16x8*)(Wl + (size_t)(dx * 64 + co) * 128 +
                                            ((sw * 64 + g * 16) ^ ((co & 7) << 4)));
                }
#pragma unroll
                for (int xf = 0; xf < 4; ++xf) {
                    const int col = xf * 16 + lm + dx;
                    b[xf] = *(const f16x8*)(Xl + (size_t)(r * 72 + col) * 128 +
                                            ((sw * 64 + g * 16) ^ ((col & 7) << 4)));
                }
#pragma unroll
                for (int cf = 0; cf < 2; ++cf)
#pragma unroll
                    for (int xf = 0; xf < 4; ++xf)
                        acc[cf][xf] = __builtin_amdgcn_mfma_f32_16x16x32_f16(
                            a[cf], b[xf], acc[cf][xf], 0, 0, 0);
            }
        }
    }

    // ---- merge k-halves
    __syncthreads();
    {
        const int mslot = r * 2 + h;
        if (sw == 1) {
#pragma unroll
            for (int cf = 0; cf < 2; ++cf)
#pragma unroll
                for (int xf = 0; xf < 4; ++xf)
                    *(f32x4*)(smem + (size_t)(mslot * 64 + lane) * 128 +
                              (((cf * 4 + xf) * 16) ^ ((lane & 7) << 4))) = acc[cf][xf];
        }
        __syncthreads();
        if (sw == 0) {
#pragma unroll
            for (int cf = 0; cf < 2; ++cf)
#pragma unroll
                for (int xf = 0; xf < 4; ++xf)
                    acc[cf][xf] += *(const f32x4*)(smem + (size_t)(mslot * 64 + lane) * 128 +
                                                   (((cf * 4 + xf) * 16) ^ ((lane & 7) << 4)));
        }
    }

    // ---- epilogue (sw=0 waves)
    if (sw == 0) {
        const int y = y0 + r;
#pragma unroll
        for (int cf = 0; cf < 2; ++cf) {
            const float4 bv = *(const float4*)(bias + h * 32 + cf * 16 + g * 4);
            if (LAYOUT == 0) {
#pragma unroll
                for (int xf = 0; xf < 4; ++xf) {
                    f16x4 pk;
#pragma unroll
                    for (int e = 0; e < 4; ++e)
                        pk[e] = (f16)((acc[cf][xf][e] + ((const float*)&bv)[e]) * oscale);
                    *(f16x4*)(dst + ((size_t)n * HW + y * W + xf * 16 + lm) * 64 +
                              h * 32 + cf * 16 + g * 4) = pk;
                }
            } else {
#pragma unroll
                for (int e = 0; e < 4; ++e) {
                    const int co = h * 32 + cf * 16 + g * 4 + e;
#pragma unroll
                    for (int xf = 0; xf < 4; ++xf)
                        dst[((size_t)(n * CR + co)) * HW + y * W + xf * 16 + lm] =
                            (f16)((acc[cf][xf][e] + ((const float*)&bv)[e]) * oscale);
                }
            }
        }
    }
}

// ------------------------------------------------- fused MFMA attention (16x16)
// Grid 512 (n, 64-j tile), 4 waves; wave owns 16 j = jt*64 + wv*16 + (lane&15).
// Q in registers; K/V double-buffered in LDS via global_load_lds (pre-swizzled src),
// prefetched one tile ahead; softmax in exp2 domain, per-column m,z in registers.
__global__ __launch_bounds__(256, 2) void attn_mfma(
    const f16* __restrict__ qT, const f16* __restrict__ kT, const f16* __restrict__ vv,
    f16* __restrict__ attu, float* __restrict__ Mcol, float* __restrict__ Zcol)
{
    const int bid0 = blockIdx.x;
    const int bid = (bid0 & 7) * 64 + (bid0 >> 3);   // XCD swizzle, 512 = 8*64
    const int jt = bid & 63;
    const int n  = bid >> 6;
    const int j0 = jt * 64;
    const int tid = threadIdx.x;
    const int wv = tid >> 6;
    const int lane = tid & 63;
    const int lm = lane & 15;
    const int g  = lane >> 4;
    const int key = (lm & 7) << 4;
    const int j = j0 + wv * 16 + lm;

    __shared__ __align__(16) f16 KV[2][2][64 * 64];   // [buf][K/V][64 rows x 128B]

    // per-lane staging source perm (pre-swizzle so linear LDS dest ends up XOR'd)
    const int rsub = lane >> 3;                 // row within 8-row segment
    const int perm = ((lane & 7) ^ rsub) << 3;  // f16 units
    const f16* kS = kT + ((size_t)n * HW) * 64;
    const f16* vS = vv + ((size_t)n * CR) * HW;

    // Q in regs: B-frag col=j, k(c) = ks*32 + g*8 + e
    f16x8 qf[2];
    {
        const f16* qp = qT + ((size_t)n * HW + j) * 64 + g * 8;
        qf[0] = *(const f16x8*)(qp);
        qf[1] = *(const f16x8*)(qp + 32);
    }

    float m = -1e30f, z = 0.f;
    f32x4 accp[4];
#pragma unroll
    for (int c = 0; c < 4; ++c) accp[c] = f32x4{0.f, 0.f, 0.f, 0.f};

    // prologue: stage tile 0 into buf 0 (per wave: 2 K segments + 2 V segments)
#pragma unroll
    for (int h = 0; h < 2; ++h) {
        const int q = 2 * wv + h;
        gl_lds16(kS + (size_t)(q * 8 + rsub) * 64 + perm, &KV[0][0][q * 512]);
        gl_lds16(vS + (size_t)(q * 8 + rsub) * HW + perm, &KV[0][1][q * 512]);
    }
    __syncthreads();

    int buf = 0;
    for (int it = 0; it < 64; ++it) {
        // ---- prefetch next tile into buf^1 (in flight across QK+softmax+PV)
        if (it < 63) {
#pragma unroll
            for (int h = 0; h < 2; ++h) {
                const int q = 2 * wv + h;
                gl_lds16(kS + (size_t)((it + 1) * 64 + q * 8 + rsub) * 64 + perm,
                         &KV[buf ^ 1][0][q * 512]);
                gl_lds16(vS + (size_t)(q * 8 + rsub) * HW + (it + 1) * 64 + perm,
                         &KV[buf ^ 1][1][q * 512]);
            }
        }

        // ---- QK: S[i][j], wave covers 64 i (4 frags) x its 16 j
        const char* Kb = (const char*)&KV[buf][0][0];
        f32x4 sacc[4];
#pragma unroll
        for (int f = 0; f < 4; ++f) sacc[f] = f32x4{0.f, 0.f, 0.f, 0.f};
        __builtin_amdgcn_s_setprio(1);
#pragma unroll
        for (int ks = 0; ks < 2; ++ks) {
            const int off = (ks * 64 + g * 16) ^ key;
#pragma unroll
            for (int f = 0; f < 4; ++f) {
                const f16x8 A = *(const f16x8*)(Kb + (f * 16 + lm) * 128 + off);
                sacc[f] = __builtin_amdgcn_mfma_f32_16x16x32_f16(A, qf[ks], sacc[f], 0, 0, 0);
            }
        }
        __builtin_amdgcn_s_setprio(0);

        // ---- online softmax (exp2 domain); column j lane-local across g via xor-shfl
        float mt = sacc[0][0];
#pragma unroll
        for (int f = 0; f < 4; ++f)
#pragma unroll
            for (int e = 0; e < 4; ++e) mt = fmaxf(mt, sacc[f][e]);
        mt = fmaxf(mt, __shfl_xor(mt, 16));
        mt = fmaxf(mt, __shfl_xor(mt, 32));
        if (__ballot(mt > m)) {        // defer-max: skip rescale when no column grew
            const float mnew = fmaxf(m, mt);
            const float rsc = exp2f(m - mnew);
            z *= rsc;
#pragma unroll
            for (int cf = 0; cf < 4; ++cf) {
                accp[cf][0] *= rsc; accp[cf][1] *= rsc;
                accp[cf][2] *= rsc; accp[cf][3] *= rsc;
            }
            m = mnew;
        }
        f16x4 p16[4];
        float zt = 0.f;
#pragma unroll
        for (int f = 0; f < 4; ++f) {
#pragma unroll
            for (int e = 0; e < 4; ++e) {
                const float ev = exp2f(sacc[f][e] - m);
                zt += ev;
                p16[f][e] = (f16)ev;
            }
        }
        zt += __shfl_xor(zt, 16);
        zt += __shfl_xor(zt, 32);
        z += zt;

        // ---- PV: att[c][j] += V[c][i-tile] * P (k=16 frags, shuffle-free)
        const char* Vb = (const char*)&KV[buf][1][0];
        __builtin_amdgcn_s_setprio(1);
#pragma unroll
        for (int cf = 0; cf < 4; ++cf) {
#pragma unroll
            for (int f = 0; f < 4; ++f) {
                const f16x4 A = *(const f16x4*)(Vb + (cf * 16 + lm) * 128 +
                                                ((f * 32 + g * 8) ^ key));
                accp[cf] = __builtin_amdgcn_mfma_f32_16x16x16f16(A, p16[f], accp[cf], 0, 0, 0);
            }
        }
        __builtin_amdgcn_s_setprio(0);

        if (it < 63) {
            __syncthreads();   // drains prefetch vmcnt + all waves done with buf
            buf ^= 1;
        }
    }

    // epilogue: attu[n][j][c] f16; Mcol/Zcol[n][j] (log2 domain)
    const size_t jbase = ((size_t)n * HW + j) * 64;
#pragma unroll
    for (int cf = 0; cf < 4; ++cf) {
        f16x4 pk;
#pragma unroll
        for (int e = 0; e < 4; ++e) pk[e] = (f16)accp[cf][e];
        *(f16x4*)(attu + jbase + cf * 16 + g * 4) = pk;
    }
    if (g == 0) {
        Mcol[(size_t)n * HW + j] = m;
        Zcol[(size_t)n * HW + j] = z;
    }
}

// ------------------------------------------------------------- global M, Z per n
__global__ __launch_bounds__(256) void reduce_kernel(
    const float* __restrict__ Mcol, const float* __restrict__ Zcol,
    float* __restrict__ Mn, float* __restrict__ Zn)
{
    const int n = blockIdx.x;
    const int tid = threadIdx.x;
    __shared__ float red[256];

    float lm = -1e30f;
    for (int j = tid; j < HW; j += 256) lm = fmaxf(lm, Mcol[(size_t)n * HW + j]);
    red[tid] = lm; __syncthreads();
    for (int s = 128; s > 0; s >>= 1) {
        if (tid < s) red[tid] = fmaxf(red[tid], red[tid + s]);
        __syncthreads();
    }
    const float M = red[0];
    __syncthreads();

    float ls = 0.f;
    for (int j = tid; j < HW; j += 256)
        ls += Zcol[(size_t)n * HW + j] * exp2f(Mcol[(size_t)n * HW + j] - M);
    red[tid] = ls; __syncthreads();
    for (int s = 128; s > 0; s >>= 1) {
        if (tid < s) red[tid] += red[tid + s];
        __syncthreads();
    }
    if (tid == 0) { Mn[n] = M; Zn[n] = red[0]; }
}

// --------------------- MFMA 1x1 conv + per-column scale + elementwise
__global__ __launch_bounds__(512) void final_mfma(
    const f16* __restrict__ attu, const float* __restrict__ Mcol,
    const float* __restrict__ Mn, const float* __restrict__ Zn,
    const float* __restrict__ watt, const float* __restrict__ batt,
    const float* __restrict__ gco, float* __restrict__ out)
{
    __shared__ __align__(16) f16 Wl[256 * 64];   // 32 KB
    __shared__ __align__(16) f16 Al[128 * 64];   // 16 KB

    const int bid0 = blockIdx.x;
    const int bid = (bid0 & 7) * 32 + (bid0 >> 3);   // XCD swizzle: n == XCD
    const int n  = bid >> 5;
    const int p0 = (bid & 31) * 128;
    const int tid = threadIdx.x;
    const int wv = tid >> 6;
    const int lane = tid & 63;
    const int lm = lane & 15;
    const int g  = lane >> 4;

#pragma unroll
    for (int t = 0; t < 8; ++t) {
        const int idx = tid + t * 512;
        const int co = idx >> 4;
        const int ch = idx & 15;
        const float4 w4 = *(const float4*)(watt + (size_t)co * 64 + ch * 4);
        f16x4 pk;
        pk[0] = (f16)w4.x; pk[1] = (f16)w4.y; pk[2] = (f16)w4.z; pk[3] = (f16)w4.w;
        *(f16x4*)((char*)Wl + co * 128 + ((ch * 8) ^ ((co & 7) << 4))) = pk;
    }
#pragma unroll
    for (int t = 0; t < 4; ++t) {
        const int idx = tid + t * 512;
        const int pp = idx >> 3;
        const int ch = idx & 7;
        *(uint4*)((char*)Al + pp * 128 + ((ch * 16) ^ ((pp & 7) << 4))) =
            *(const uint4*)(attu + ((size_t)n * HW + p0 + pp) * 64 + ch * 8);
    }
    __syncthreads();

    f32x4 acc[2][8];
#pragma unroll
    for (int cf = 0; cf < 2; ++cf)
#pragma unroll
        for (int pf = 0; pf < 8; ++pf) acc[cf][pf] = f32x4{0.f, 0.f, 0.f, 0.f};

#pragma unroll
    for (int ks = 0; ks < 2; ++ks) {
        const int off = ks * 64 + g * 16;
        f16x8 A[2], B[8];
#pragma unroll
        for (int cf = 0; cf < 2; ++cf) {
            const int co = wv * 32 + cf * 16 + lm;
            A[cf] = *(const f16x8*)((char*)Wl + co * 128 + (off ^ ((co & 7) << 4)));
        }
#pragma unroll
        for (int pf = 0; pf < 8; ++pf) {
            const int pp = pf * 16 + lm;
            B[pf] = *(const f16x8*)((char*)Al + pp * 128 + (off ^ ((pp & 7) << 4)));
        }
#pragma unroll
        for (int cf = 0; cf < 2; ++cf)
#pragma unroll
            for (int pf = 0; pf < 8; ++pf)
                acc[cf][pf] = __builtin_amdgcn_mfma_f32_16x16x32_f16(
                    A[cf], B[pf], acc[cf][pf], 0, 0, 0);
    }

    const float M = Mn[n];
    const float Zi = 1.f / Zn[n];
    float ecol[8];
#pragma unroll
    for (int pf = 0; pf < 8; ++pf)
        ecol[pf] = exp2f(Mcol[(size_t)n * HW + p0 + pf * 16 + lm] - M) * Zi;

#pragma unroll
    for (int cf = 0; cf < 2; ++cf) {
#pragma unroll
        for (int e = 0; e < 4; ++e) {
            const int co = wv * 32 + cf * 16 + g * 4 + e;
            const float bb = batt[co] + 1.f;
            const float* gsrc = gco + (size_t)(n * CIN + co) * HW + p0 + lm;
            float* dstp = out + (size_t)(n * CIN + co) * HW + p0 + lm;
#pragma unroll
            for (int pf = 0; pf < 8; ++pf) {
                const float gvv = gsrc[pf * 16];
                dstp[pf * 16] = gvv * (acc[cf][pf][e] * ecol[pf] + bb);
            }
        }
    }
}

// --------------------------------------------------------------------- launch
extern "C" void kernel_launch(void* const* d_in, const int* in_sizes, int n_in,
                              void* d_out, int out_size, void* d_ws, size_t ws_size,
                              hipStream_t stream)
{
    (void)in_sizes; (void)n_in; (void)out_size; (void)ws_size;
    const float* fm   = (const float*)d_in[0];
    const float* gco  = (const float*)d_in[1];
    const float* wq   = (const float*)d_in[2];
    const float* bq   = (const float*)d_in[3];
    const float* wk   = (const float*)d_in[4];
    const float* bk   = (const float*)d_in[5];
    const float* wv   = (const float*)d_in[6];
    const float* bv   = (const float*)d_in[7];
    const float* watt = (const float*)d_in[8];
    const float* batt = (const float*)d_in[9];
    float* out = (float*)d_out;

    // f16 scratch in d_out (28.8 MB of 33.5 MB): qT|kT|v|fmT, all dead before final.
    f16* qT   = (f16*)out;            // [n][p][c]   4 MB  (pre-scaled by log2e)
    f16* kT   = qT + QKV;             // [n][p][c]   4 MB
    f16* vvb  = kT + QKV;             // [n][c][p]   4 MB
    f16* fmT  = vvb + QKV;            // [n][p][ci]  16.8 MB

    // ws: wTq | wTk | wTv | attu | Mcol | Zcol | Mn | Zn  (7.18 MB, proven layout)
    unsigned char* wsb = (unsigned char*)d_ws;
    f16* wTq = (f16*)(wsb);
    f16* wTk = (f16*)(wsb + 294912);
    f16* wTv = (f16*)(wsb + 1114112);
    f16* attu = (f16*)(wsb + 2719744);                        // [n][p][c] f16, 4 MB
    float* Mcol = (float*)(wsb + 6914048);                    // [n][4096] f32 (log2)
    float* Zcol = (float*)(wsb + 7045120);
    float* Mn   = (float*)(wsb + 7176192);
    float* Zn   = (float*)(wsb + 7176224);

    const float LOG2E = 1.4426950408889634f;

    prep_w<<<576, 256, 0, stream>>>(wq, wTq, 9);
    prep_w<<<1600, 256, 0, stream>>>(wk, wTk, 25);
    prep_w<<<3136, 256, 0, stream>>>(wv, wTv, 49);
    transpose_fm<<<NB * 64, 256, 0, stream>>>(fm, fmT);

    conv_mfma<3, 0><<<256, 512, 0, stream>>>(fmT, wTq, bq, qT, LOG2E);
    conv_mfma<5, 0><<<256, 512, 0, stream>>>(fmT, wTk, bk, kT, 1.0f);
    conv_mfma<7, 1><<<256, 512, 0, stream>>>(fmT, wTv, bv, vvb, 1.0f);

    attn_mfma<<<NB * 64, 256, 0, stream>>>(qT, kT, vvb, attu, Mcol, Zcol);
    reduce_kernel<<<NB, 256, 0, stream>>>(Mcol, Zcol, Mn, Zn);
    final_mfma<<<256, 512, 0, stream>>>(attu, Mcol, Mn, Zn, watt, batt, gco, out);
}

// Round 9
// 237.481 us; speedup vs baseline: 1.0693x; 1.0089x over previous
//
#include <hip/hip_runtime.h>
#include <math.h>

#define NB 8
#define CIN 256
#define CR 64
#define H 64
#define W 64
#define HW 4096

typedef _Float16 f16;
typedef _Float16 f16x8 __attribute__((ext_vector_type(8)));
typedef _Float16 f16x4 __attribute__((ext_vector_type(4)));
typedef float f32x4 __attribute__((ext_vector_type(4)));

static const size_t QKV = (size_t)NB * CR * HW;   // 2,097,152 elems per q/k/v buffer

// async global->LDS, 16B per lane, LDS dest = uniform base + lane*16
static __device__ __forceinline__ void gl_lds16(const f16* g, f16* l) {
    __builtin_amdgcn_global_load_lds(
        (const __attribute__((address_space(1))) void*)g,
        (__attribute__((address_space(3))) void*)l, 16, 0, 0);
}

// ------------------------------------------------------------- weight prep
// w[co][ci][dy][dx] fp32 -> wT[dy*K+dx][co][ci] fp16
__global__ __launch_bounds__(256) void prep_w(
    const float* __restrict__ src, f16* __restrict__ dst, int KK)
{
    int idx = blockIdx.x * 256 + threadIdx.x;    // < 64*256*KK
    int ci = idx & 255;
    int co = (idx >> 8) & 63;
    int off = idx >> 14;
    dst[((size_t)(off * 64 + co)) * 256 + ci] = (f16)src[((size_t)(co * 256 + ci)) * KK + off];
}

// ------------------------------------------------------- feature-map transpose
// fm f32 [n][ci][y][x] -> fmT f16 [n][y*64+x][ci]
__global__ __launch_bounds__(256) void transpose_fm(
    const float* __restrict__ fm, f16* __restrict__ fmT)
{
    const int y = blockIdx.x & 63;
    const int n = blockIdx.x >> 6;
    const int tid = threadIdx.x;
    __shared__ f16x4 tile[64 * 64];   // [x][slot], slot XOR-swizzled by x
    const int xw = tid & 63;
    const int wv = tid >> 6;
    const float* s0 = fm + ((size_t)n * CIN) * HW + y * W + xw;
#pragma unroll
    for (int cc = 0; cc < 16; ++cc) {
        const int slot = wv * 16 + cc;            // ci = slot*4 + e
        const float* s = s0 + (size_t)(slot * 4) * HW;
        f16x4 pk;
#pragma unroll
        for (int e = 0; e < 4; ++e) pk[e] = (f16)s[(size_t)e * HW];
        tile[xw * 64 + (slot ^ xw)] = pk;
    }
    __syncthreads();
    f16x4* dst = (f16x4*)fmT + ((size_t)n * HW + y * W) * 64;
#pragma unroll
    for (int it = 0; it < 16; ++it) {
        const int idx = tid + it * 256;           // < 4096
        const int x = idx >> 6;
        const int slot = idx & 63;
        dst[x * 64 + slot] = tile[x * 64 + (slot ^ x)];
    }
}

// ---------------------------------------------------------- MFMA conv K x K
// Grid 256 blocks (n, 2-row group), 512 threads = 8 waves (row r, co-half h, k-half sw).
// LAYOUT 0: dst [n][p][c] f16 (q, k).  LAYOUT 1: dst [n][c][p] f16 (v).
// oscale: output scale (log2e for q to move softmax into exp2 domain).
template<int K, int LAYOUT>
__global__ __launch_bounds__(512) void conv_mfma(
    const f16* __restrict__ fmT, const f16* __restrict__ wT,
    const float* __restrict__ bias, f16* __restrict__ dst, float oscale)
{
    constexpr int P = K / 2;
    constexpr int XBYTES = 2 * 72 * 128;          // 18432
    constexpr int WBYTES = K * 64 * 128;
    constexpr int TBYTES = XBYTES + WBYTES;
    constexpr int SBYTES = (TBYTES > 32768) ? TBYTES : 32768;
    __shared__ __align__(16) unsigned char smem[SBYTES];
    unsigned char* Xl = smem;
    unsigned char* Wl = smem + XBYTES;

    const int bid0 = blockIdx.x;
    const int bid = (bid0 & 7) * 32 + (bid0 >> 3);   // XCD swizzle, 256 = 8*32
    const int n  = bid >> 5;
    const int y0 = (bid & 31) * 2;
    const int tid = threadIdx.x;
    const int w = tid >> 6;
    const int lane = tid & 63;
    const int r  = w >> 2;        // row within block
    const int h  = (w >> 1) & 1;  // co half
    const int sw = w & 1;         // k half (32-ci sub-chunk)
    const int lm = lane & 15;
    const int g  = lane >> 4;

    // zero halo columns once (cols [0,P) and [64+P,72) of both slots)
    if (tid < 128) {
        const int sl = tid >> 6;
        const int cidx = (tid >> 3) & 7;
        const int chunk = tid & 7;
        const int col = (cidx < P) ? cidx : (64 + cidx);
        *(uint4*)(Xl + (size_t)(sl * 72 + col) * 128 + chunk * 16) = uint4{0, 0, 0, 0};
    }

    f32x4 acc[2][4];
#pragma unroll
    for (int i = 0; i < 2; ++i)
#pragma unroll
        for (int jx = 0; jx < 4; ++jx) acc[i][jx] = f32x4{0.f, 0.f, 0.f, 0.f};

    for (int dy = 0; dy < K; ++dy) {
        for (int ch = 0; ch < 4; ++ch) {
            __syncthreads();
            // ---- stage X: 2 rows x 64 x x 64 ci(ch) = 1024 uint4, 2/thread
#pragma unroll
            for (int p = 0; p < 2; ++p) {
                const int idx = tid + p * 512;
                const int sl = idx >> 9;
                const int x = (idx >> 3) & 63;
                const int chunk = idx & 7;
                const int iy = y0 + sl + dy - P;
                uint4 val = uint4{0, 0, 0, 0};
                if (iy >= 0 && iy < H)
                    val = *(const uint4*)(fmT + ((size_t)n * HW + iy * 64 + x) * 256 +
                                          ch * 64 + chunk * 8);
                *(uint4*)(Xl + (size_t)(sl * 72 + x + P) * 128 +
                          ((chunk * 16) ^ (((x + P) & 7) << 4))) = val;
            }
            // ---- stage W: K*512 uint4, K/thread
#pragma unroll
            for (int p = 0; p < K; ++p) {
                const int idx = tid + p * 512;
                const int cig = idx & 7;
                const int co  = (idx >> 3) & 63;
                const int dx  = idx >> 9;
                const f16* s = wT + ((size_t)((dy * K + dx) * 64 + co)) * 256 + ch * 64 + cig * 8;
                *(uint4*)(Wl + (size_t)(dx * 64 + co) * 128 +
                          ((cig * 16) ^ ((co & 7) << 4))) = *(const uint4*)s;
            }
            __syncthreads();
            // ---- compute
#pragma unroll
            for (int dx = 0; dx < K; ++dx) {
                f16x8 a[2], b[4];
#pragma unroll
                for (int cf = 0; cf < 2; ++cf) {
                    const int co = h * 32 + cf * 16 + lm;
                    a[cf] = *(const f16x8*)(Wl + (size_t)(dx * 64 + co) * 128 +
                                            ((sw * 64 + g * 16) ^ ((co & 7) << 4)));
                }
#pragma unroll
                for (int xf = 0; xf < 4; ++xf) {
                    const int col = xf * 16 + lm + dx;
                    b[xf] = *(const f16x8*)(Xl + (size_t)(r * 72 + col) * 128 +
                                            ((sw * 64 + g * 16) ^ ((col & 7) << 4)));
                }
#pragma unroll
                for (int cf = 0; cf < 2; ++cf)
#pragma unroll
                    for (int xf = 0; xf < 4; ++xf)
                        acc[cf][xf] = __builtin_amdgcn_mfma_f32_16x16x32_f16(
                            a[cf], b[xf], acc[cf][xf], 0, 0, 0);
            }
        }
    }

    // ---- merge k-halves
    __syncthreads();
    {
        const int mslot = r * 2 + h;
        if (sw == 1) {
#pragma unroll
            for (int cf = 0; cf < 2; ++cf)
#pragma unroll
                for (int xf = 0; xf < 4; ++xf)
                    *(f32x4*)(smem + (size_t)(mslot * 64 + lane) * 128 +
                              (((cf * 4 + xf) * 16) ^ ((lane & 7) << 4))) = acc[cf][xf];
        }
        __syncthreads();
        if (sw == 0) {
#pragma unroll
            for (int cf = 0; cf < 2; ++cf)
#pragma unroll
                for (int xf = 0; xf < 4; ++xf)
                    acc[cf][xf] += *(const f32x4*)(smem + (size_t)(mslot * 64 + lane) * 128 +
                                                   (((cf * 4 + xf) * 16) ^ ((lane & 7) << 4)));
        }
    }

    // ---- epilogue (sw=0 waves)
    if (sw == 0) {
        const int y = y0 + r;
#pragma unroll
        for (int cf = 0; cf < 2; ++cf) {
            const float4 bv = *(const float4*)(bias + h * 32 + cf * 16 + g * 4);
            if (LAYOUT == 0) {
#pragma unroll
                for (int xf = 0; xf < 4; ++xf) {
                    f16x4 pk;
#pragma unroll
                    for (int e = 0; e < 4; ++e)
                        pk[e] = (f16)((acc[cf][xf][e] + ((const float*)&bv)[e]) * oscale);
                    *(f16x4*)(dst + ((size_t)n * HW + y * W + xf * 16 + lm) * 64 +
                              h * 32 + cf * 16 + g * 4) = pk;
                }
            } else {
#pragma unroll
                for (int e = 0; e < 4; ++e) {
                    const int co = h * 32 + cf * 16 + g * 4 + e;
#pragma unroll
                    for (int xf = 0; xf < 4; ++xf)
                        dst[((size_t)(n * CR + co)) * HW + y * W + xf * 16 + lm] =
                            (f16)((acc[cf][xf][e] + ((const float*)&bv)[e]) * oscale);
                }
            }
        }
    }
}

// ------------------------------------------------- fused MFMA attention (16x16)
// Grid 512 (n, 64-j tile), 4 waves; wave owns 16 j = jt*64 + wv*16 + (lane&15).
// Q in registers; K/V double-buffered across four STATIC __shared__ arrays
// (compile-time addresses -> no may-alias stall between prefetch DMA and ds_reads).
// Each step: ds_read ALL K/V frags to regs -> issue prefetch -> softmax -> PV -> barrier.
__global__ __launch_bounds__(256, 2) void attn_mfma(
    const f16* __restrict__ qT, const f16* __restrict__ kT, const f16* __restrict__ vv,
    f16* __restrict__ attu, float* __restrict__ Mcol, float* __restrict__ Zcol)
{
    const int bid0 = blockIdx.x;
    const int bid = (bid0 & 7) * 64 + (bid0 >> 3);   // XCD swizzle, 512 = 8*64
    const int jt = bid & 63;
    const int n  = bid >> 6;
    const int j0 = jt * 64;
    const int tid = threadIdx.x;
    const int wv = tid >> 6;
    const int lane = tid & 63;
    const int lm = lane & 15;
    const int g  = lane >> 4;
    const int key = (lm & 7) << 4;
    const int j = j0 + wv * 16 + lm;

    __shared__ __align__(16) f16 K0[64 * 64];
    __shared__ __align__(16) f16 V0[64 * 64];
    __shared__ __align__(16) f16 K1[64 * 64];
    __shared__ __align__(16) f16 V1[64 * 64];

    // per-lane staging source perm (pre-swizzle so linear LDS dest ends up XOR'd)
    const int rsub = lane >> 3;                 // row within 8-row segment
    const int perm = ((lane & 7) ^ rsub) << 3;  // f16 units
    const f16* kS = kT + ((size_t)n * HW) * 64;
    const f16* vS = vv + ((size_t)n * CR) * HW;
    const int seg = 2 * wv;                     // this wave's first 8-row segment

    // Q in regs: B-frag col=j, k(c) = ks*32 + g*8 + e
    f16x8 qf[2];
    {
        const f16* qp = qT + ((size_t)n * HW + j) * 64 + g * 8;
        qf[0] = *(const f16x8*)(qp);
        qf[1] = *(const f16x8*)(qp + 32);
    }

    float m = -1e30f, z = 0.f;
    f32x4 accp[4];
#pragma unroll
    for (int c = 0; c < 4; ++c) accp[c] = f32x4{0.f, 0.f, 0.f, 0.f};

    // prologue: stage tile 0 into K0/V0 (per wave: 2 K segments + 2 V segments)
#pragma unroll
    for (int h = 0; h < 2; ++h) {
        const int q = seg + h;
        gl_lds16(kS + (size_t)(q * 8 + rsub) * 64 + perm, &K0[q * 512]);
        gl_lds16(vS + (size_t)(q * 8 + rsub) * HW + perm, &V0[q * 512]);
    }
    __syncthreads();

#define ATTN_STEP(CK, CV, NK, NV, IT)                                            \
    do {                                                                         \
        const char* Kb = (const char*)(CK);                                      \
        const char* Vb = (const char*)(CV);                                      \
        /* all LDS reads first: K frags (8 x b128) + V frags (16 x b64) */       \
        f16x8 kf0[4], kf1[4];                                                    \
        f16x4 vf[4][4];                                                          \
        _Pragma("unroll")                                                        \
        for (int f = 0; f < 4; ++f) {                                            \
            kf0[f] = *(const f16x8*)(Kb + (f * 16 + lm) * 128 + ((g * 16) ^ key)); \
            kf1[f] = *(const f16x8*)(Kb + (f * 16 + lm) * 128 + ((64 + g * 16) ^ key)); \
        }                                                                        \
        _Pragma("unroll")                                                        \
        for (int cf = 0; cf < 4; ++cf)                                           \
            _Pragma("unroll")                                                    \
            for (int f = 0; f < 4; ++f)                                          \
                vf[cf][f] = *(const f16x4*)(Vb + (cf * 16 + lm) * 128 +          \
                                            ((f * 32 + g * 8) ^ key));           \
        /* QK */                                                                 \
        f32x4 sacc[4];                                                           \
        _Pragma("unroll")                                                        \
        for (int f = 0; f < 4; ++f) sacc[f] = f32x4{0.f, 0.f, 0.f, 0.f};         \
        __builtin_amdgcn_s_setprio(1);                                           \
        _Pragma("unroll")                                                        \
        for (int f = 0; f < 4; ++f) {                                            \
            sacc[f] = __builtin_amdgcn_mfma_f32_16x16x32_f16(kf0[f], qf[0], sacc[f], 0, 0, 0); \
            sacc[f] = __builtin_amdgcn_mfma_f32_16x16x32_f16(kf1[f], qf[1], sacc[f], 0, 0, 0); \
        }                                                                        \
        __builtin_amdgcn_s_setprio(0);                                           \
        /* prefetch next tile (no ds_read after this point in the step) */      \
        if ((IT) < 63) {                                                         \
            _Pragma("unroll")                                                    \
            for (int h = 0; h < 2; ++h) {                                        \
                const int q = seg + h;                                           \
                gl_lds16(kS + (size_t)(((IT) + 1) * 64 + q * 8 + rsub) * 64 + perm, \
                         &(NK)[q * 512]);                                        \
                gl_lds16(vS + (size_t)(q * 8 + rsub) * HW + ((IT) + 1) * 64 + perm, \
                         &(NV)[q * 512]);                                        \
            }                                                                    \
        }                                                                        \
        /* online softmax (exp2 domain) */                                       \
        float mt = sacc[0][0];                                                   \
        _Pragma("unroll")                                                        \
        for (int f = 0; f < 4; ++f)                                              \
            _Pragma("unroll")                                                    \
            for (int e = 0; e < 4; ++e) mt = fmaxf(mt, sacc[f][e]);              \
        mt = fmaxf(mt, __shfl_xor(mt, 16));                                      \
        mt = fmaxf(mt, __shfl_xor(mt, 32));                                      \
        if (__ballot(mt > m)) {                                                  \
            const float mnew = fmaxf(m, mt);                                     \
            const float rsc = exp2f(m - mnew);                                   \
            z *= rsc;                                                            \
            _Pragma("unroll")                                                    \
            for (int cf = 0; cf < 4; ++cf) {                                     \
                accp[cf][0] *= rsc; accp[cf][1] *= rsc;                          \
                accp[cf][2] *= rsc; accp[cf][3] *= rsc;                          \
            }                                                                    \
            m = mnew;                                                            \
        }                                                                        \
        f16x4 p16[4];                                                            \
        float zt = 0.f;                                                          \
        _Pragma("unroll")                                                        \
        for (int f = 0; f < 4; ++f) {                                            \
            _Pragma("unroll")                                                    \
            for (int e = 0; e < 4; ++e) {                                        \
                const float ev = exp2f(sacc[f][e] - m);                          \
                zt += ev;                                                        \
                p16[f][e] = (f16)ev;                                             \
            }                                                                    \
        }                                                                        \
        zt += __shfl_xor(zt, 16);                                                \
        zt += __shfl_xor(zt, 32);                                                \
        z += zt;                                                                 \
        /* PV from registers */                                                  \
        __builtin_amdgcn_s_setprio(1);                                           \
        _Pragma("unroll")                                                        \
        for (int cf = 0; cf < 4; ++cf)                                           \
            _Pragma("unroll")                                                    \
            for (int f = 0; f < 4; ++f)                                          \
                accp[cf] = __builtin_amdgcn_mfma_f32_16x16x16f16(                \
                    vf[cf][f], p16[f], accp[cf], 0, 0, 0);                       \
        __builtin_amdgcn_s_setprio(0);                                           \
        __syncthreads();                                                         \
    } while (0)

    for (int itp = 0; itp < 32; ++itp) {
        const int it0 = itp * 2;
        ATTN_STEP(K0, V0, K1, V1, it0);
        ATTN_STEP(K1, V1, K0, V0, it0 + 1);
    }
#undef ATTN_STEP

    // epilogue: attu[n][j][c] f16; Mcol/Zcol[n][j] (log2 domain)
    const size_t jbase = ((size_t)n * HW + j) * 64;
#pragma unroll
    for (int cf = 0; cf < 4; ++cf) {
        f16x4 pk;
#pragma unroll
        for (int e = 0; e < 4; ++e) pk[e] = (f16)accp[cf][e];
        *(f16x4*)(attu + jbase + cf * 16 + g * 4) = pk;
    }
    if (g == 0) {
        Mcol[(size_t)n * HW + j] = m;
        Zcol[(size_t)n * HW + j] = z;
    }
}

// ------------------------------------------------------------- global M, Z per n
__global__ __launch_bounds__(256) void reduce_kernel(
    const float* __restrict__ Mcol, const float* __restrict__ Zcol,
    float* __restrict__ Mn, float* __restrict__ Zn)
{
    const int n = blockIdx.x;
    const int tid = threadIdx.x;
    __shared__ float red[256];

    float lm = -1e30f;
    for (int j = tid; j < HW; j += 256) lm = fmaxf(lm, Mcol[(size_t)n * HW + j]);
    red[tid] = lm; __syncthreads();
    for (int s = 128; s > 0; s >>= 1) {
        if (tid < s) red[tid] = fmaxf(red[tid], red[tid + s]);
        __syncthreads();
    }
    const float M = red[0];
    __syncthreads();

    float ls = 0.f;
    for (int j = tid; j < HW; j += 256)
        ls += Zcol[(size_t)n * HW + j] * exp2f(Mcol[(size_t)n * HW + j] - M);
    red[tid] = ls; __syncthreads();
    for (int s = 128; s > 0; s >>= 1) {
        if (tid < s) red[tid] += red[tid + s];
        __syncthreads();
    }
    if (tid == 0) { Mn[n] = M; Zn[n] = red[0]; }
}

// --------------------- MFMA 1x1 conv + per-column scale + elementwise
__global__ __launch_bounds__(512) void final_mfma(
    const f16* __restrict__ attu, const float* __restrict__ Mcol,
    const float* __restrict__ Mn, const float* __restrict__ Zn,
    const float* __restrict__ watt, const float* __restrict__ batt,
    const float* __restrict__ gco, float* __restrict__ out)
{
    __shared__ __align__(16) f16 Wl[256 * 64];   // 32 KB
    __shared__ __align__(16) f16 Al[128 * 64];   // 16 KB

    const int bid0 = blockIdx.x;
    const int bid = (bid0 & 7) * 32 + (bid0 >> 3);   // XCD swizzle: n == XCD
    const int n  = bid >> 5;
    const int p0 = (bid & 31) * 128;
    const int tid = threadIdx.x;
    const int wv = tid >> 6;
    const int lane = tid & 63;
    const int lm = lane & 15;
    const int g  = lane >> 4;

#pragma unroll
    for (int t = 0; t < 8; ++t) {
        const int idx = tid + t * 512;
        const int co = idx >> 4;
        const int ch = idx & 15;
        const float4 w4 = *(const float4*)(watt + (size_t)co * 64 + ch * 4);
        f16x4 pk;
        pk[0] = (f16)w4.x; pk[1] = (f16)w4.y; pk[2] = (f16)w4.z; pk[3] = (f16)w4.w;
        *(f16x4*)((char*)Wl + co * 128 + ((ch * 8) ^ ((co & 7) << 4))) = pk;
    }
#pragma unroll
    for (int t = 0; t < 4; ++t) {
        const int idx = tid + t * 512;
        const int pp = idx >> 3;
        const int ch = idx & 7;
        *(uint4*)((char*)Al + pp * 128 + ((ch * 16) ^ ((pp & 7) << 4))) =
            *(const uint4*)(attu + ((size_t)n * HW + p0 + pp) * 64 + ch * 8);
    }
    __syncthreads();

    f32x4 acc[2][8];
#pragma unroll
    for (int cf = 0; cf < 2; ++cf)
#pragma unroll
        for (int pf = 0; pf < 8; ++pf) acc[cf][pf] = f32x4{0.f, 0.f, 0.f, 0.f};

#pragma unroll
    for (int ks = 0; ks < 2; ++ks) {
        const int off = ks * 64 + g * 16;
        f16x8 A[2], B[8];
#pragma unroll
        for (int cf = 0; cf < 2; ++cf) {
            const int co = wv * 32 + cf * 16 + lm;
            A[cf] = *(const f16x8*)((char*)Wl + co * 128 + (off ^ ((co & 7) << 4)));
        }
#pragma unroll
        for (int pf = 0; pf < 8; ++pf) {
            const int pp = pf * 16 + lm;
            B[pf] = *(const f16x8*)((char*)Al + pp * 128 + (off ^ ((pp & 7) << 4)));
        }
#pragma unroll
        for (int cf = 0; cf < 2; ++cf)
#pragma unroll
            for (int pf = 0; pf < 8; ++pf)
                acc[cf][pf] = __builtin_amdgcn_mfma_f32_16x16x32_f16(
                    A[cf], B[pf], acc[cf][pf], 0, 0, 0);
    }

    const float M = Mn[n];
    const float Zi = 1.f / Zn[n];
    float ecol[8];
#pragma unroll
    for (int pf = 0; pf < 8; ++pf)
        ecol[pf] = exp2f(Mcol[(size_t)n * HW + p0 + pf * 16 + lm] - M) * Zi;

#pragma unroll
    for (int cf = 0; cf < 2; ++cf) {
#pragma unroll
        for (int e = 0; e < 4; ++e) {
            const int co = wv * 32 + cf * 16 + g * 4 + e;
            const float bb = batt[co] + 1.f;
            const float* gsrc = gco + (size_t)(n * CIN + co) * HW + p0 + lm;
            float* dstp = out + (size_t)(n * CIN + co) * HW + p0 + lm;
#pragma unroll
            for (int pf = 0; pf < 8; ++pf) {
                const float gvv = gsrc[pf * 16];
                dstp[pf * 16] = gvv * (acc[cf][pf][e] * ecol[pf] + bb);
            }
        }
    }
}

// --------------------------------------------------------------------- launch
extern "C" void kernel_launch(void* const* d_in, const int* in_sizes, int n_in,
                              void* d_out, int out_size, void* d_ws, size_t ws_size,
                              hipStream_t stream)
{
    (void)in_sizes; (void)n_in; (void)out_size; (void)ws_size;
    const float* fm   = (const float*)d_in[0];
    const float* gco  = (const float*)d_in[1];
    const float* wq   = (const float*)d_in[2];
    const float* bq   = (const float*)d_in[3];
    const float* wk   = (const float*)d_in[4];
    const float* bk   = (const float*)d_in[5];
    const float* wv   = (const float*)d_in[6];
    const float* bv   = (const float*)d_in[7];
    const float* watt = (const float*)d_in[8];
    const float* batt = (const float*)d_in[9];
    float* out = (float*)d_out;

    // f16 scratch in d_out (28.8 MB of 33.5 MB): qT|kT|v|fmT, all dead before final.
    f16* qT   = (f16*)out;            // [n][p][c]   4 MB  (pre-scaled by log2e)
    f16* kT   = qT + QKV;             // [n][p][c]   4 MB
    f16* vvb  = kT + QKV;             // [n][c][p]   4 MB
    f16* fmT  = vvb + QKV;            // [n][p][ci]  16.8 MB

    // ws: wTq | wTk | wTv | attu | Mcol | Zcol | Mn | Zn  (7.18 MB, proven layout)
    unsigned char* wsb = (unsigned char*)d_ws;
    f16* wTq = (f16*)(wsb);
    f16* wTk = (f16*)(wsb + 294912);
    f16* wTv = (f16*)(wsb + 1114112);
    f16* attu = (f16*)(wsb + 2719744);                        // [n][p][c] f16, 4 MB
    float* Mcol = (float*)(wsb + 6914048);                    // [n][4096] f32 (log2)
    float* Zcol = (float*)(wsb + 7045120);
    float* Mn   = (float*)(wsb + 7176192);
    float* Zn   = (float*)(wsb + 7176224);

    const float LOG2E = 1.4426950408889634f;

    prep_w<<<576, 256, 0, stream>>>(wq, wTq, 9);
    prep_w<<<1600, 256, 0, stream>>>(wk, wTk, 25);
    prep_w<<<3136, 256, 0, stream>>>(wv, wTv, 49);
    transpose_fm<<<NB * 64, 256, 0, stream>>>(fm, fmT);

    conv_mfma<3, 0><<<256, 512, 0, stream>>>(fmT, wTq, bq, qT, LOG2E);
    conv_mfma<5, 0><<<256, 512, 0, stream>>>(fmT, wTk, bk, kT, 1.0f);
    conv_mfma<7, 1><<<256, 512, 0, stream>>>(fmT, wTv, bv, vvb, 1.0f);

    attn_mfma<<<NB * 64, 256, 0, stream>>>(qT, kT, vvb, attu, Mcol, Zcol);
    reduce_kernel<<<NB, 256, 0, stream>>>(Mcol, Zcol, Mn, Zn);
    final_mfma<<<256, 512, 0, stream>>>(attu, Mcol, Mn, Zn, watt, batt, gco, out);
}